// Round 6
// baseline (146.850 us; speedup 1.0000x reference)
//
#include <hip/hip_runtime.h>
#include <hip/hip_bf16.h>

#define N_NODES 50000
#define N_EDGES 800000
#define N_FEATS 64
#define EB (N_EDGES / 4)      // int4 groups
#define NBUCK 64              // destination buckets
#define BRANGE 784            // nodes per bucket (64*784 = 50176 >= 50000)
#define SUBS 4                // sub-workgroups per bucket in streaming kernels
#define SRANGE 196            // BRANGE / SUBS nodes owned per WG
#define CAPB 14336            // records per bucket (mean 12500, sigma ~111 -> 16 sigma)
#define SB 256
#define NB ((N_NODES + SB - 1) / SB)

// ================= shared kernels =================

__global__ void k_zero_i(int* __restrict__ p, int n) {
    int i = blockIdx.x * blockDim.x + threadIdx.x;
    if (i < n) p[i] = 0;
}

// z[node] = dinv[node] * dot(x[node,:], w) -- one wave per node, coalesced
__global__ void k_matvec_z(const float* __restrict__ x, const float* __restrict__ w,
                           const float* __restrict__ dinv, float* __restrict__ z, int n) {
    int lane = threadIdx.x & 63;
    int node = blockIdx.x * (blockDim.x >> 6) + (threadIdx.x >> 6);
    if (node >= n) return;
    float v = x[node * N_FEATS + lane] * w[lane];
    #pragma unroll
    for (int off = 32; off > 0; off >>= 1) v += __shfl_down(v, off, 64);
    if (lane == 0) z[node] = dinv[node] * v;
}

// ================= bucketed path (primary) =================

// One pass: bin edges by destination bucket. Ranks via LDS atomics; ONE global
// atomic per (block,bucket) instead of one per edge; records appended in
// ~contiguous runs so L2 write-back stays near-payload.
__global__ void k_bucketize(const int* __restrict__ row, const int* __restrict__ col,
                            int* __restrict__ gcur, int2* __restrict__ recs) {
    __shared__ int cnt[NBUCK];
    __shared__ int base[NBUCK];
    int t = threadIdx.x;
    if (t < NBUCK) cnt[t] = 0;
    __syncthreads();
    int g = blockIdx.x * blockDim.x + t;
    bool valid = (g < EB);
    int4 r, c;
    int bk[4], rk[4];
    if (valid) {
        c = ((const int4*)col)[g];
        r = ((const int4*)row)[g];
        bk[0] = c.x / BRANGE; bk[1] = c.y / BRANGE;
        bk[2] = c.z / BRANGE; bk[3] = c.w / BRANGE;
        rk[0] = atomicAdd(&cnt[bk[0]], 1);
        rk[1] = atomicAdd(&cnt[bk[1]], 1);
        rk[2] = atomicAdd(&cnt[bk[2]], 1);
        rk[3] = atomicAdd(&cnt[bk[3]], 1);
    }
    __syncthreads();
    if (t < NBUCK && cnt[t] > 0) base[t] = atomicAdd(&gcur[t], cnt[t]);
    __syncthreads();
    if (valid) {
        int cc[4] = {c.x, c.y, c.z, c.w};
        int rr[4] = {r.x, r.y, r.z, r.w};
        #pragma unroll
        for (int i = 0; i < 4; i++) {
            int slot = base[bk[i]] + rk[i];
            if (slot < CAPB) recs[(size_t)bk[i] * CAPB + slot] = make_int2(cc[i], rr[i]);
        }
    }
}

// Per-(bucket,subrange) WG streams bucket records, counts owned destinations in
// LDS, emits dinv coalesced. Grid = NBUCK*SUBS, block = 512.
__global__ void k_deg_dinv(const int* __restrict__ gcur, const int2* __restrict__ recs,
                           float* __restrict__ dinv) {
    __shared__ int cnt[SRANGE];
    int t = threadIdx.x;
    int bucket = blockIdx.x / SUBS;
    int sub    = blockIdx.x % SUBS;
    int own0   = bucket * BRANGE + sub * SRANGE;
    if (t < SRANGE) cnt[t] = 0;
    __syncthreads();
    int sz = min(gcur[bucket], CAPB);
    const int2* rb = recs + (size_t)bucket * CAPB;
    for (int e = t; e < sz; e += blockDim.x) {
        int lc = rb[e].x - own0;
        if ((unsigned)lc < (unsigned)SRANGE) atomicAdd(&cnt[lc], 1);
    }
    __syncthreads();
    if (t < SRANGE) {
        int node = own0 + t;
        if (node < N_NODES) dinv[node] = rsqrtf((float)(cnt[t] + 1));
    }
}

// Hop: LDS fp32 accumulators over owned subrange; stream bucket records, add
// z[src] for owned destinations; finalize with self term + dinv scaling.
//   FINAL=false: out[i] = dinv^2 * (z[i] + sum)
//   FINAL=true : out[i] = dinv   * (z[i] + sum) + bias
template <bool FINAL>
__global__ void k_hop(const int* __restrict__ gcur, const int2* __restrict__ recs,
                      const float* __restrict__ dinv, const float* __restrict__ zin,
                      float* __restrict__ out, const float* __restrict__ bptr) {
    __shared__ float acc[SRANGE];
    int t = threadIdx.x;
    int bucket = blockIdx.x / SUBS;
    int sub    = blockIdx.x % SUBS;
    int own0   = bucket * BRANGE + sub * SRANGE;
    if (t < SRANGE) acc[t] = 0.0f;
    __syncthreads();
    int sz = min(gcur[bucket], CAPB);
    const int2* rb = recs + (size_t)bucket * CAPB;
    for (int e = t; e < sz; e += blockDim.x) {
        int2 rec = rb[e];
        int lc = rec.x - own0;
        if ((unsigned)lc < (unsigned)SRANGE) atomicAdd(&acc[lc], zin[rec.y]);
    }
    __syncthreads();
    if (t < SRANGE) {
        int node = own0 + t;
        if (node < N_NODES) {
            float di = dinv[node];
            float v  = zin[node] + acc[t];
            out[node] = FINAL ? (di * v + bptr[0]) : (di * di * v);
        }
    }
}

// ================= tight-CSR fallback (R4 pipeline, verified) =================

__global__ void k_hist(const int* __restrict__ col, int* __restrict__ hist) {
    int t = blockIdx.x * blockDim.x + threadIdx.x;
    if (t >= EB) return;
    int4 c = ((const int4*)col)[t];
    atomicAdd(&hist[c.x], 1);
    atomicAdd(&hist[c.y], 1);
    atomicAdd(&hist[c.z], 1);
    atomicAdd(&hist[c.w], 1);
}

__global__ void k_scan_partial(const int* __restrict__ hist, int* __restrict__ bsum,
                               float* __restrict__ dinv) {
    __shared__ int s[SB];
    int t = threadIdx.x;
    int i = blockIdx.x * SB + t;
    int v = 0;
    if (i < N_NODES) { v = hist[i]; dinv[i] = rsqrtf((float)(v + 1)); }
    s[t] = v;
    __syncthreads();
    for (int off = SB / 2; off > 0; off >>= 1) {
        if (t < off) s[t] += s[t + off];
        __syncthreads();
    }
    if (t == 0) bsum[blockIdx.x] = s[0];
}

__global__ void k_scan_bsum(const int* __restrict__ bsum, int* __restrict__ boff) {
    __shared__ int s[SB];
    int t = threadIdx.x;
    int v = (t < NB) ? bsum[t] : 0;
    s[t] = v;
    __syncthreads();
    for (int off = 1; off < SB; off <<= 1) {
        int u = (t >= off) ? s[t - off] : 0;
        __syncthreads();
        s[t] += u;
        __syncthreads();
    }
    if (t < NB) boff[t] = s[t] - v;
}

__global__ void k_scan_final(const int* __restrict__ hist, const int* __restrict__ boff,
                             int* __restrict__ cursor) {
    __shared__ int s[SB];
    int t = threadIdx.x;
    int i = blockIdx.x * SB + t;
    int v = (i < N_NODES) ? hist[i] : 0;
    s[t] = v;
    __syncthreads();
    for (int off = 1; off < SB; off <<= 1) {
        int u = (t >= off) ? s[t - off] : 0;
        __syncthreads();
        s[t] += u;
        __syncthreads();
    }
    if (i < N_NODES) cursor[i] = boff[blockIdx.x] + s[t] - v;
}

__global__ void k_scatter(const int* __restrict__ row, const int* __restrict__ col,
                          int* __restrict__ cursor, int* __restrict__ csr) {
    int t = blockIdx.x * blockDim.x + threadIdx.x;
    if (t >= EB) return;
    int4 r = ((const int4*)row)[t];
    int4 c = ((const int4*)col)[t];
    csr[atomicAdd(&cursor[c.x], 1)] = r.x;
    csr[atomicAdd(&cursor[c.y], 1)] = r.y;
    csr[atomicAdd(&cursor[c.z], 1)] = r.z;
    csr[atomicAdd(&cursor[c.w], 1)] = r.w;
}

template <bool FINAL>
__global__ void k_gather(const int* __restrict__ cursor, const int* __restrict__ csr,
                         const float* __restrict__ dinv, const float* __restrict__ zin,
                         float* __restrict__ out, const float* __restrict__ bptr, int n) {
    int i = blockIdx.x * blockDim.x + threadIdx.x;
    if (i >= n) return;
    int end = cursor[i];
    int start = (i == 0) ? 0 : cursor[i - 1];
    float acc = zin[i];
    for (int j = start; j < end; j++) acc += zin[csr[j]];
    float di = dinv[i];
    if (FINAL) out[i] = di * acc + bptr[0];
    else       out[i] = di * di * acc;
}

// ================= launch =================

extern "C" void kernel_launch(void* const* d_in, const int* in_sizes, int n_in,
                              void* d_out, int out_size, void* d_ws, size_t ws_size,
                              hipStream_t stream) {
    const float* x  = (const float*)d_in[0];   // [N, 64]
    const int*   ei = (const int*)d_in[1];     // [2, E]
    const float* W  = (const float*)d_in[2];   // [1, 64]
    const float* b  = (const float*)d_in[3];   // [1]
    float* out = (float*)d_out;                // [N]

    const int* row = ei;                       // sources
    const int* col = ei + N_EDGES;             // destinations

    const int B   = 256;
    const int gN  = (N_NODES + B - 1) / B;
    const int gE4 = (EB + B - 1) / B;

    // bucketed ws: gcur[64] (pad to 64 ints for alignment) | recs[NBUCK*CAPB] int2 | dinv | z0 | z1
    const size_t buck_bytes = 64 * 4 + (size_t)NBUCK * CAPB * 8 + 3 * (size_t)N_NODES * 4;

    if (ws_size >= buck_bytes) {
        int*   gcur = (int*)d_ws;
        int2*  recs = (int2*)(gcur + 64);
        float* dinv = (float*)(recs + (size_t)NBUCK * CAPB);
        float* z0   = dinv + N_NODES;
        float* z1   = z0 + N_NODES;

        k_zero_i<<<1, 64, 0, stream>>>(gcur, NBUCK);
        k_bucketize<<<gE4, B, 0, stream>>>(row, col, gcur, recs);
        k_deg_dinv<<<NBUCK * SUBS, 512, 0, stream>>>(gcur, recs, dinv);
        k_matvec_z<<<(N_NODES + 3) / 4, B, 0, stream>>>(x, W, dinv, z0, N_NODES);

        k_hop<false><<<NBUCK * SUBS, 512, 0, stream>>>(gcur, recs, dinv, z0, z1, nullptr);
        k_hop<false><<<NBUCK * SUBS, 512, 0, stream>>>(gcur, recs, dinv, z1, z0, nullptr);
        k_hop<true ><<<NBUCK * SUBS, 512, 0, stream>>>(gcur, recs, dinv, z0, out, b);
    } else {
        // tight fallback (R4): hist[N] | cursor[N] | csr[E] | dinv[N] | z0[N] | z1[N] | bsum | boff
        int*   hist   = (int*)d_ws;
        int*   cursor = hist + N_NODES;
        int*   csr    = cursor + N_NODES;
        float* dinv   = (float*)(csr + N_EDGES);
        float* z0     = dinv + N_NODES;
        float* z1     = z0 + N_NODES;
        int*   bsum   = (int*)(z1 + N_NODES);
        int*   boff   = bsum + NB;

        k_zero_i<<<gN, B, 0, stream>>>(hist, N_NODES);
        k_hist<<<gE4, B, 0, stream>>>(col, hist);
        k_scan_partial<<<NB, SB, 0, stream>>>(hist, bsum, dinv);
        k_scan_bsum<<<1, SB, 0, stream>>>(bsum, boff);
        k_scan_final<<<NB, SB, 0, stream>>>(hist, boff, cursor);
        k_scatter<<<gE4, B, 0, stream>>>(row, col, cursor, csr);
        k_matvec_z<<<(N_NODES + 3) / 4, B, 0, stream>>>(x, W, dinv, z0, N_NODES);

        k_gather<false><<<gN, B, 0, stream>>>(cursor, csr, dinv, z0, z1, nullptr, N_NODES);
        k_gather<false><<<gN, B, 0, stream>>>(cursor, csr, dinv, z1, z0, nullptr, N_NODES);
        k_gather<true ><<<gN, B, 0, stream>>>(cursor, csr, dinv, z0, out, b, N_NODES);
    }
}